// Round 1
// baseline (206.729 us; speedup 1.0000x reference)
//
#include <hip/hip_runtime.h>
#include <math.h>

#define D_MODEL 1024
#define N_RES   2048
#define BATCH   32
constexpr float INV_2PI = 0.15915494309189535f;

// ---------------------------------------------------------------------------
// Kernel A: x_collapsed[b][d] = sum_k [x_real|x_imag][b][k] * ipw[d][k] + bias[d]
// grid 256 blocks (4 d each), block 256 = 4 waves; wave w handles batches w*8..w*8+7
// lanes split over k (coalesced float4 loads).
// ---------------------------------------------------------------------------
__global__ __launch_bounds__(256) void kA(const float* __restrict__ xr,
                                          const float* __restrict__ xi,
                                          const float* __restrict__ ipw,
                                          const float* __restrict__ bias,
                                          float* __restrict__ xc) {
  const int tid  = threadIdx.x;
  const int lane = tid & 63;
  const int wave = tid >> 6;
  const int d0 = blockIdx.x * 4;
  const int b0 = wave * 8;

  float acc[8][4];
#pragma unroll
  for (int b = 0; b < 8; ++b)
#pragma unroll
    for (int d = 0; d < 4; ++d) acc[b][d] = 0.f;

  const float4* xr4  = (const float4*)xr;   // row = 256 float4
  const float4* xi4  = (const float4*)xi;
  const float4* ipw4 = (const float4*)ipw;  // row = 512 float4

  // k in [0,1024): x_real
#pragma unroll
  for (int i = 0; i < 4; ++i) {
    const int j = lane + 64 * i;            // float4 index in [0,256)
    float4 w4[4];
#pragma unroll
    for (int d = 0; d < 4; ++d) w4[d] = ipw4[(d0 + d) * 512 + j];
#pragma unroll
    for (int b = 0; b < 8; ++b) {
      float4 x4 = xr4[(b0 + b) * 256 + j];
#pragma unroll
      for (int d = 0; d < 4; ++d) {
        acc[b][d] += x4.x * w4[d].x + x4.y * w4[d].y + x4.z * w4[d].z + x4.w * w4[d].w;
      }
    }
  }
  // k in [1024,2048): x_imag
#pragma unroll
  for (int i = 0; i < 4; ++i) {
    const int j = lane + 64 * i;
    float4 w4[4];
#pragma unroll
    for (int d = 0; d < 4; ++d) w4[d] = ipw4[(d0 + d) * 512 + 256 + j];
#pragma unroll
    for (int b = 0; b < 8; ++b) {
      float4 x4 = xi4[(b0 + b) * 256 + j];
#pragma unroll
      for (int d = 0; d < 4; ++d) {
        acc[b][d] += x4.x * w4[d].x + x4.y * w4[d].y + x4.z * w4[d].z + x4.w * w4[d].w;
      }
    }
  }

#pragma unroll
  for (int b = 0; b < 8; ++b) {
#pragma unroll
    for (int d = 0; d < 4; ++d) {
      float v = acc[b][d];
#pragma unroll
      for (int m = 32; m >= 1; m >>= 1) v += __shfl_xor(v, m, 64);
      if (lane == 0) xc[(b0 + b) * D_MODEL + d0 + d] = v + bias[d0 + d];
    }
  }
}

// ---------------------------------------------------------------------------
// Kernel B: for each resonator n:
//   r[b][d] = (xc[b][d]/(1+|W[n][d]|) + B[n][d] + t[b]) * INV_2PI
//   cos_sum[b][n] = sum_d cos(2*pi*r);  sin_sum[b][n] = sum_d sin(2*pi*r)
// grid 2048 (one n per block), block 256 = 4 waves; wave handles 8 batches,
// lanes split over d. Per-n coefficients staged once in LDS (amortize rcp 32x).
// ---------------------------------------------------------------------------
__global__ __launch_bounds__(256) void kB(const float* __restrict__ xc,
                                          const float* __restrict__ W,
                                          const float* __restrict__ Bm,
                                          const float* __restrict__ t,
                                          float* __restrict__ cos_sum,
                                          float* __restrict__ sin_sum) {
  __shared__ float a_s[D_MODEL];  // INV_2PI / (1+|W|)
  __shared__ float c_s[D_MODEL];  // B * INV_2PI
  const int n   = blockIdx.x;
  const int tid = threadIdx.x;

  {
    const float4* W4 = (const float4*)(W + (size_t)n * D_MODEL);
    const float4* B4 = (const float4*)(Bm + (size_t)n * D_MODEL);
    float4 w4 = W4[tid];
    float4 b4 = B4[tid];
    float4 a4, c4;
    a4.x = INV_2PI / (1.f + fabsf(w4.x));
    a4.y = INV_2PI / (1.f + fabsf(w4.y));
    a4.z = INV_2PI / (1.f + fabsf(w4.z));
    a4.w = INV_2PI / (1.f + fabsf(w4.w));
    c4.x = b4.x * INV_2PI;
    c4.y = b4.y * INV_2PI;
    c4.z = b4.z * INV_2PI;
    c4.w = b4.w * INV_2PI;
    ((float4*)a_s)[tid] = a4;
    ((float4*)c_s)[tid] = c4;
  }
  __syncthreads();

  const int lane = tid & 63;
  const int wave = tid >> 6;
  const int b0 = wave * 8;
  const float4* as4 = (const float4*)a_s;
  const float4* cs4 = (const float4*)c_s;

  for (int bb = 0; bb < 8; ++bb) {
    const int b = b0 + bb;
    const float t2 = t[b] * INV_2PI;   // wave-uniform -> scalar
    const float4* x4p = (const float4*)(xc + (size_t)b * D_MODEL);
    float ss = 0.f, cc = 0.f;
#pragma unroll
    for (int i = 0; i < 4; ++i) {
      const int j = lane + 64 * i;     // float4 idx in [0,256)
      float4 x4 = x4p[j];
      float4 a4 = as4[j];
      float4 c4 = cs4[j];
      {
        float r = x4.x * a4.x + c4.x + t2;
        float fr = r - floorf(r);
        ss += __builtin_amdgcn_sinf(fr);
        cc += __builtin_amdgcn_cosf(fr);
      }
      {
        float r = x4.y * a4.y + c4.y + t2;
        float fr = r - floorf(r);
        ss += __builtin_amdgcn_sinf(fr);
        cc += __builtin_amdgcn_cosf(fr);
      }
      {
        float r = x4.z * a4.z + c4.z + t2;
        float fr = r - floorf(r);
        ss += __builtin_amdgcn_sinf(fr);
        cc += __builtin_amdgcn_cosf(fr);
      }
      {
        float r = x4.w * a4.w + c4.w + t2;
        float fr = r - floorf(r);
        ss += __builtin_amdgcn_sinf(fr);
        cc += __builtin_amdgcn_cosf(fr);
      }
    }
#pragma unroll
    for (int m = 32; m >= 1; m >>= 1) {
      ss += __shfl_xor(ss, m, 64);
      cc += __shfl_xor(cc, m, 64);
    }
    if (lane == 0) {
      cos_sum[(size_t)b * N_RES + n] = cc;
      sin_sum[(size_t)b * N_RES + n] = ss;
    }
  }
}

// ---------------------------------------------------------------------------
// Kernel C: out_real[b][d] = silu(sum_n cos_sum[b][n]*orw[d][n]),
//           out_imag[b][d] = silu(sum_n sin_sum[b][n]*oiw[d][n])
// grid 512 blocks (2 d each), block 256 = 4 waves; wave handles 8 batches,
// lanes split over n.
// ---------------------------------------------------------------------------
__device__ __forceinline__ float silu(float v) {
  return v / (1.f + __expf(-v));
}

__global__ __launch_bounds__(256) void kC(const float* __restrict__ cos_sum,
                                          const float* __restrict__ sin_sum,
                                          const float* __restrict__ orw,
                                          const float* __restrict__ oiw,
                                          float* __restrict__ out) {
  const int tid  = threadIdx.x;
  const int lane = tid & 63;
  const int wave = tid >> 6;
  const int d0 = blockIdx.x * 2;
  const int b0 = wave * 8;

  float ar[8][2], ai[8][2];
#pragma unroll
  for (int b = 0; b < 8; ++b)
#pragma unroll
    for (int d = 0; d < 2; ++d) { ar[b][d] = 0.f; ai[b][d] = 0.f; }

#pragma unroll
  for (int i = 0; i < 8; ++i) {
    const int j = lane + 64 * i;   // float4 idx over n in [0,512)
    float4 wr[2], wi[2];
#pragma unroll
    for (int d = 0; d < 2; ++d) {
      wr[d] = ((const float4*)(orw + (size_t)(d0 + d) * N_RES))[j];
      wi[d] = ((const float4*)(oiw + (size_t)(d0 + d) * N_RES))[j];
    }
#pragma unroll
    for (int b = 0; b < 8; ++b) {
      float4 cs = ((const float4*)(cos_sum + (size_t)(b0 + b) * N_RES))[j];
      float4 sn = ((const float4*)(sin_sum + (size_t)(b0 + b) * N_RES))[j];
#pragma unroll
      for (int d = 0; d < 2; ++d) {
        ar[b][d] += cs.x * wr[d].x + cs.y * wr[d].y + cs.z * wr[d].z + cs.w * wr[d].w;
        ai[b][d] += sn.x * wi[d].x + sn.y * wi[d].y + sn.z * wi[d].z + sn.w * wi[d].w;
      }
    }
  }

#pragma unroll
  for (int b = 0; b < 8; ++b) {
#pragma unroll
    for (int d = 0; d < 2; ++d) {
      float vr = ar[b][d];
      float vi = ai[b][d];
#pragma unroll
      for (int m = 32; m >= 1; m >>= 1) {
        vr += __shfl_xor(vr, m, 64);
        vi += __shfl_xor(vi, m, 64);
      }
      if (lane == 0) {
        out[(size_t)(b0 + b) * D_MODEL + d0 + d] = silu(vr);
        out[(size_t)BATCH * D_MODEL + (size_t)(b0 + b) * D_MODEL + d0 + d] = silu(vi);
      }
    }
  }
}

extern "C" void kernel_launch(void* const* d_in, const int* in_sizes, int n_in,
                              void* d_out, int out_size, void* d_ws, size_t ws_size,
                              hipStream_t stream) {
  const float* xr   = (const float*)d_in[0];
  const float* xi   = (const float*)d_in[1];
  const float* t    = (const float*)d_in[2];
  const float* ipw  = (const float*)d_in[3];
  const float* bias = (const float*)d_in[4];
  const float* W    = (const float*)d_in[5];
  const float* Bm   = (const float*)d_in[6];
  const float* orw  = (const float*)d_in[7];
  const float* oiw  = (const float*)d_in[8];
  float* out = (float*)d_out;

  float* xc      = (float*)d_ws;             // 32*1024
  float* cos_sum = xc + BATCH * D_MODEL;     // 32*2048
  float* sin_sum = cos_sum + BATCH * N_RES;  // 32*2048

  kA<<<D_MODEL / 4, 256, 0, stream>>>(xr, xi, ipw, bias, xc);
  kB<<<N_RES, 256, 0, stream>>>(xc, W, Bm, t, cos_sum, sin_sum);
  kC<<<D_MODEL / 2, 256, 0, stream>>>(cos_sum, sin_sum, orw, oiw, out);
}

// Round 2
// 174.133 us; speedup vs baseline: 1.1872x; 1.1872x over previous
//
#include <hip/hip_runtime.h>
#include <math.h>

#define D_MODEL 1024
#define N_RES   2048
#define BATCH   32
constexpr float INV_2PI = 0.15915494309189535f;

// ---------------------------------------------------------------------------
// Kernel A: x_collapsed[b][d] = sum_k [x_real|x_imag][b][k] * ipw[d][k] + bias[d]
// grid 256 blocks (4 d each), block 256 = 4 waves; wave w handles batches w*8..w*8+7
// lanes split over k (coalesced float4 loads).
// #pragma unroll 1 on chunk loops: full unroll made the compiler hoist all
// chunk loads -> VGPR blowout + scratch spill (R0 kC lesson: WRITE_SIZE 84MB).
// ---------------------------------------------------------------------------
__global__ __launch_bounds__(256) void kA(const float* __restrict__ xr,
                                          const float* __restrict__ xi,
                                          const float* __restrict__ ipw,
                                          const float* __restrict__ bias,
                                          float* __restrict__ xc) {
  const int tid  = threadIdx.x;
  const int lane = tid & 63;
  const int wave = tid >> 6;
  const int d0 = blockIdx.x * 4;
  const int b0 = wave * 8;

  float acc[8][4];
#pragma unroll
  for (int b = 0; b < 8; ++b)
#pragma unroll
    for (int d = 0; d < 4; ++d) acc[b][d] = 0.f;

  const float4* xr4  = (const float4*)xr;   // row = 256 float4
  const float4* xi4  = (const float4*)xi;
  const float4* ipw4 = (const float4*)ipw;  // row = 512 float4

  // k in [0,1024): x_real
#pragma unroll 1
  for (int i = 0; i < 4; ++i) {
    const int j = lane + 64 * i;            // float4 index in [0,256)
    float4 w4[4];
#pragma unroll
    for (int d = 0; d < 4; ++d) w4[d] = ipw4[(d0 + d) * 512 + j];
#pragma unroll
    for (int b = 0; b < 8; ++b) {
      float4 x4 = xr4[(b0 + b) * 256 + j];
#pragma unroll
      for (int d = 0; d < 4; ++d) {
        acc[b][d] += x4.x * w4[d].x + x4.y * w4[d].y + x4.z * w4[d].z + x4.w * w4[d].w;
      }
    }
  }
  // k in [1024,2048): x_imag
#pragma unroll 1
  for (int i = 0; i < 4; ++i) {
    const int j = lane + 64 * i;
    float4 w4[4];
#pragma unroll
    for (int d = 0; d < 4; ++d) w4[d] = ipw4[(d0 + d) * 512 + 256 + j];
#pragma unroll
    for (int b = 0; b < 8; ++b) {
      float4 x4 = xi4[(b0 + b) * 256 + j];
#pragma unroll
      for (int d = 0; d < 4; ++d) {
        acc[b][d] += x4.x * w4[d].x + x4.y * w4[d].y + x4.z * w4[d].z + x4.w * w4[d].w;
      }
    }
  }

#pragma unroll
  for (int b = 0; b < 8; ++b) {
#pragma unroll
    for (int d = 0; d < 4; ++d) {
      float v = acc[b][d];
#pragma unroll
      for (int m = 32; m >= 1; m >>= 1) v += __shfl_xor(v, m, 64);
      if (lane == 0) xc[(b0 + b) * D_MODEL + d0 + d] = v + bias[d0 + d];
    }
  }
}

// ---------------------------------------------------------------------------
// Kernel B: for each resonator n:
//   r[b][d] = (xc[b][d]/(1+|W[n][d]|) + B[n][d] + t[b]) * INV_2PI
//   cos_sum[b][n] = sum_d cos(2*pi*r);  sin_sum[b][n] = sum_d sin(2*pi*r)
// grid 2048 (one n per block), block 256 = 4 waves; wave handles 8 batches,
// lanes split over d. Per-n coefficients staged once in LDS (amortize rcp 32x).
// ---------------------------------------------------------------------------
__global__ __launch_bounds__(256) void kB(const float* __restrict__ xc,
                                          const float* __restrict__ W,
                                          const float* __restrict__ Bm,
                                          const float* __restrict__ t,
                                          float* __restrict__ cos_sum,
                                          float* __restrict__ sin_sum) {
  __shared__ float a_s[D_MODEL];  // INV_2PI / (1+|W|)
  __shared__ float c_s[D_MODEL];  // B * INV_2PI
  const int n   = blockIdx.x;
  const int tid = threadIdx.x;

  {
    const float4* W4 = (const float4*)(W + (size_t)n * D_MODEL);
    const float4* B4 = (const float4*)(Bm + (size_t)n * D_MODEL);
    float4 w4 = W4[tid];
    float4 b4 = B4[tid];
    float4 a4, c4;
    a4.x = INV_2PI / (1.f + fabsf(w4.x));
    a4.y = INV_2PI / (1.f + fabsf(w4.y));
    a4.z = INV_2PI / (1.f + fabsf(w4.z));
    a4.w = INV_2PI / (1.f + fabsf(w4.w));
    c4.x = b4.x * INV_2PI;
    c4.y = b4.y * INV_2PI;
    c4.z = b4.z * INV_2PI;
    c4.w = b4.w * INV_2PI;
    ((float4*)a_s)[tid] = a4;
    ((float4*)c_s)[tid] = c4;
  }
  __syncthreads();

  const int lane = tid & 63;
  const int wave = tid >> 6;
  const int b0 = wave * 8;
  const float4* as4 = (const float4*)a_s;
  const float4* cs4 = (const float4*)c_s;

#pragma unroll 1
  for (int bb = 0; bb < 8; ++bb) {
    const int b = b0 + bb;
    const float t2 = t[b] * INV_2PI;   // wave-uniform -> scalar
    const float4* x4p = (const float4*)(xc + (size_t)b * D_MODEL);
    float ss = 0.f, cc = 0.f;
#pragma unroll
    for (int i = 0; i < 4; ++i) {
      const int j = lane + 64 * i;     // float4 idx in [0,256)
      float4 x4 = x4p[j];
      float4 a4 = as4[j];
      float4 c4 = cs4[j];
      {
        float r = x4.x * a4.x + c4.x + t2;
        float fr = r - floorf(r);
        ss += __builtin_amdgcn_sinf(fr);
        cc += __builtin_amdgcn_cosf(fr);
      }
      {
        float r = x4.y * a4.y + c4.y + t2;
        float fr = r - floorf(r);
        ss += __builtin_amdgcn_sinf(fr);
        cc += __builtin_amdgcn_cosf(fr);
      }
      {
        float r = x4.z * a4.z + c4.z + t2;
        float fr = r - floorf(r);
        ss += __builtin_amdgcn_sinf(fr);
        cc += __builtin_amdgcn_cosf(fr);
      }
      {
        float r = x4.w * a4.w + c4.w + t2;
        float fr = r - floorf(r);
        ss += __builtin_amdgcn_sinf(fr);
        cc += __builtin_amdgcn_cosf(fr);
      }
    }
#pragma unroll
    for (int m = 32; m >= 1; m >>= 1) {
      ss += __shfl_xor(ss, m, 64);
      cc += __shfl_xor(cc, m, 64);
    }
    if (lane == 0) {
      cos_sum[(size_t)b * N_RES + n] = cc;
      sin_sum[(size_t)b * N_RES + n] = ss;
    }
  }
}

// ---------------------------------------------------------------------------
// Kernel C: out_real[b][d] = silu(sum_n cos_sum[b][n]*orw[d][n]),
//           out_imag[b][d] = silu(sum_n sin_sum[b][n]*oiw[d][n])
// grid 256 blocks (4 d each, both components), block 256 = 4 waves; wave
// handles 8 batches, lanes split over n. Outer n-chunk loop is unroll 1:
// R0's full unroll hoisted 8 iterations of loads -> 256 VGPRs + 84MB of
// scratch-spill writes (kC was 82us at 10% occupancy).
// ---------------------------------------------------------------------------
__device__ __forceinline__ float silu(float v) {
  return v / (1.f + __expf(-v));
}

__global__ __launch_bounds__(256) void kC(const float* __restrict__ cos_sum,
                                          const float* __restrict__ sin_sum,
                                          const float* __restrict__ orw,
                                          const float* __restrict__ oiw,
                                          float* __restrict__ out) {
  const int tid  = threadIdx.x;
  const int lane = tid & 63;
  const int wave = tid >> 6;
  const int d0 = blockIdx.x * 4;
  const int b0 = wave * 8;

  float ar[8][4], ai[8][4];
#pragma unroll
  for (int b = 0; b < 8; ++b)
#pragma unroll
    for (int d = 0; d < 4; ++d) { ar[b][d] = 0.f; ai[b][d] = 0.f; }

#pragma unroll 1
  for (int i = 0; i < 8; ++i) {
    const int j = lane + 64 * i;   // float4 idx over n in [0,512)
    float4 wr[4], wi[4];
#pragma unroll
    for (int d = 0; d < 4; ++d) {
      wr[d] = ((const float4*)(orw + (size_t)(d0 + d) * N_RES))[j];
      wi[d] = ((const float4*)(oiw + (size_t)(d0 + d) * N_RES))[j];
    }
#pragma unroll
    for (int b = 0; b < 8; ++b) {
      float4 cs = ((const float4*)(cos_sum + (size_t)(b0 + b) * N_RES))[j];
      float4 sn = ((const float4*)(sin_sum + (size_t)(b0 + b) * N_RES))[j];
#pragma unroll
      for (int d = 0; d < 4; ++d) {
        ar[b][d] += cs.x * wr[d].x + cs.y * wr[d].y + cs.z * wr[d].z + cs.w * wr[d].w;
        ai[b][d] += sn.x * wi[d].x + sn.y * wi[d].y + sn.z * wi[d].z + sn.w * wi[d].w;
      }
    }
  }

#pragma unroll
  for (int b = 0; b < 8; ++b) {
#pragma unroll
    for (int d = 0; d < 4; ++d) {
      float vr = ar[b][d];
      float vi = ai[b][d];
#pragma unroll
      for (int m = 32; m >= 1; m >>= 1) {
        vr += __shfl_xor(vr, m, 64);
        vi += __shfl_xor(vi, m, 64);
      }
      if (lane == 0) {
        out[(size_t)(b0 + b) * D_MODEL + d0 + d] = silu(vr);
        out[(size_t)BATCH * D_MODEL + (size_t)(b0 + b) * D_MODEL + d0 + d] = silu(vi);
      }
    }
  }
}

extern "C" void kernel_launch(void* const* d_in, const int* in_sizes, int n_in,
                              void* d_out, int out_size, void* d_ws, size_t ws_size,
                              hipStream_t stream) {
  const float* xr   = (const float*)d_in[0];
  const float* xi   = (const float*)d_in[1];
  const float* t    = (const float*)d_in[2];
  const float* ipw  = (const float*)d_in[3];
  const float* bias = (const float*)d_in[4];
  const float* W    = (const float*)d_in[5];
  const float* Bm   = (const float*)d_in[6];
  const float* orw  = (const float*)d_in[7];
  const float* oiw  = (const float*)d_in[8];
  float* out = (float*)d_out;

  float* xc      = (float*)d_ws;             // 32*1024
  float* cos_sum = xc + BATCH * D_MODEL;     // 32*2048
  float* sin_sum = cos_sum + BATCH * N_RES;  // 32*2048

  kA<<<D_MODEL / 4, 256, 0, stream>>>(xr, xi, ipw, bias, xc);
  kB<<<N_RES, 256, 0, stream>>>(xc, W, Bm, t, cos_sum, sin_sum);
  kC<<<D_MODEL / 2 / 2, 256, 0, stream>>>(cos_sum, sin_sum, orw, oiw, out);
}

// Round 3
// 163.538 us; speedup vs baseline: 1.2641x; 1.0648x over previous
//
#include <hip/hip_runtime.h>
#include <math.h>

#define D_MODEL 1024
#define N_RES   2048
#define BATCH   32
constexpr float INV_2PI = 0.15915494309189535f;

// ws layout (floats):
//   xc      : [32][1024]          @ 0
//   cos_sum : [32][2048]          @ 32K
//   sin_sum : [32][2048]          @ 96K
//   pa (kA) : [2][32][1024]       @ 160K
//   pr (kC) : [4][32][1024]       @ 224K
//   pi (kC) : [4][32][1024]       @ 352K
#define WS_XC 0
#define WS_CS (32 * 1024)
#define WS_SS (WS_CS + 32 * 2048)
#define WS_PA (WS_SS + 32 * 2048)
#define WS_PR (WS_PA + 2 * 32 * 1024)
#define WS_PI (WS_PR + 4 * 32 * 1024)

// ---------------------------------------------------------------------------
// kA_partial: split-K half of x_collapsed. blockIdx = dtile(256) + 256*kc(2).
// kc=0 -> x_real vs ipw[:, 0:1024]; kc=1 -> x_imag vs ipw[:, 1024:2048].
// 512 blocks (vs 256 monolithic) -> latency hiding. R2 lesson: 256-block
// grids run at 4 waves/CU and stall on L2 latency (kC was 43us, VALU 11%).
// ---------------------------------------------------------------------------
__global__ __launch_bounds__(256) void kA_partial(const float* __restrict__ xr,
                                                  const float* __restrict__ xi,
                                                  const float* __restrict__ ipw,
                                                  float* __restrict__ pa) {
  const int tid  = threadIdx.x;
  const int lane = tid & 63;
  const int wave = tid >> 6;
  const int d0 = (blockIdx.x & 255) * 4;
  const int kc = blockIdx.x >> 8;
  const int b0 = wave * 8;

  const float4* x4p  = (const float4*)(kc ? xi : xr);  // 256 f4 per row
  const float4* ipw4 = (const float4*)ipw;             // 512 f4 per row
  const int woff = kc * 256;

  float acc[8][4];
#pragma unroll
  for (int b = 0; b < 8; ++b)
#pragma unroll
    for (int d = 0; d < 4; ++d) acc[b][d] = 0.f;

#pragma unroll 1
  for (int i = 0; i < 4; ++i) {
    const int j = lane + 64 * i;   // f4 idx in [0,256)
    float4 w4[4];
#pragma unroll
    for (int d = 0; d < 4; ++d) w4[d] = ipw4[(d0 + d) * 512 + woff + j];
#pragma unroll
    for (int b = 0; b < 8; ++b) {
      float4 x4 = x4p[(b0 + b) * 256 + j];
#pragma unroll
      for (int d = 0; d < 4; ++d) {
        acc[b][d] += x4.x * w4[d].x + x4.y * w4[d].y + x4.z * w4[d].z + x4.w * w4[d].w;
      }
    }
  }

#pragma unroll
  for (int b = 0; b < 8; ++b) {
#pragma unroll
    for (int d = 0; d < 4; ++d) {
      float v = acc[b][d];
#pragma unroll
      for (int m = 32; m >= 1; m >>= 1) v += __shfl_xor(v, m, 64);
      if (lane == 0) pa[(size_t)(kc * BATCH + b0 + b) * D_MODEL + d0 + d] = v;
    }
  }
}

// kA2: xc = pa[0] + pa[1] + bias. 8192 float4 -> 32 blocks.
__global__ __launch_bounds__(256) void kA2(const float* __restrict__ pa,
                                           const float* __restrict__ bias,
                                           float* __restrict__ xc) {
  const int idx = blockIdx.x * 256 + threadIdx.x;  // f4 idx over 32*256
  const float4* pa4 = (const float4*)pa;
  const float4* b4p = (const float4*)bias;
  float4 a = pa4[idx];
  float4 b = pa4[8192 + idx];
  float4 c = b4p[idx & 255];
  float4 r;
  r.x = a.x + b.x + c.x;
  r.y = a.y + b.y + c.y;
  r.z = a.z + b.z + c.z;
  r.w = a.w + b.w + c.w;
  ((float4*)xc)[idx] = r;
}

// ---------------------------------------------------------------------------
// Kernel B: per resonator n: theta/(2pi) = xc*a + c + t2; sum sin/cos over d.
// 2048 blocks x 4 waves = full occupancy already. Per-n coeffs staged in LDS.
// ---------------------------------------------------------------------------
__global__ __launch_bounds__(256) void kB(const float* __restrict__ xc,
                                          const float* __restrict__ W,
                                          const float* __restrict__ Bm,
                                          const float* __restrict__ t,
                                          float* __restrict__ cos_sum,
                                          float* __restrict__ sin_sum) {
  __shared__ float a_s[D_MODEL];  // INV_2PI / (1+|W|)
  __shared__ float c_s[D_MODEL];  // B * INV_2PI
  const int n   = blockIdx.x;
  const int tid = threadIdx.x;

  {
    const float4* W4 = (const float4*)(W + (size_t)n * D_MODEL);
    const float4* B4 = (const float4*)(Bm + (size_t)n * D_MODEL);
    float4 w4 = W4[tid];
    float4 b4 = B4[tid];
    float4 a4, c4;
    a4.x = INV_2PI / (1.f + fabsf(w4.x));
    a4.y = INV_2PI / (1.f + fabsf(w4.y));
    a4.z = INV_2PI / (1.f + fabsf(w4.z));
    a4.w = INV_2PI / (1.f + fabsf(w4.w));
    c4.x = b4.x * INV_2PI;
    c4.y = b4.y * INV_2PI;
    c4.z = b4.z * INV_2PI;
    c4.w = b4.w * INV_2PI;
    ((float4*)a_s)[tid] = a4;
    ((float4*)c_s)[tid] = c4;
  }
  __syncthreads();

  const int lane = tid & 63;
  const int wave = tid >> 6;
  const int b0 = wave * 8;
  const float4* as4 = (const float4*)a_s;
  const float4* cs4 = (const float4*)c_s;

#pragma unroll 1
  for (int bb = 0; bb < 8; ++bb) {
    const int b = b0 + bb;
    const float t2 = t[b] * INV_2PI;
    const float4* x4p = (const float4*)(xc + (size_t)b * D_MODEL);
    float ss = 0.f, cc = 0.f;
#pragma unroll
    for (int i = 0; i < 4; ++i) {
      const int j = lane + 64 * i;
      float4 x4 = x4p[j];
      float4 a4 = as4[j];
      float4 c4 = cs4[j];
      {
        float r = x4.x * a4.x + c4.x + t2;
        float fr = r - floorf(r);
        ss += __builtin_amdgcn_sinf(fr);
        cc += __builtin_amdgcn_cosf(fr);
      }
      {
        float r = x4.y * a4.y + c4.y + t2;
        float fr = r - floorf(r);
        ss += __builtin_amdgcn_sinf(fr);
        cc += __builtin_amdgcn_cosf(fr);
      }
      {
        float r = x4.z * a4.z + c4.z + t2;
        float fr = r - floorf(r);
        ss += __builtin_amdgcn_sinf(fr);
        cc += __builtin_amdgcn_cosf(fr);
      }
      {
        float r = x4.w * a4.w + c4.w + t2;
        float fr = r - floorf(r);
        ss += __builtin_amdgcn_sinf(fr);
        cc += __builtin_amdgcn_cosf(fr);
      }
    }
#pragma unroll
    for (int m = 32; m >= 1; m >>= 1) {
      ss += __shfl_xor(ss, m, 64);
      cc += __shfl_xor(cc, m, 64);
    }
    if (lane == 0) {
      cos_sum[(size_t)b * N_RES + n] = cc;
      sin_sum[(size_t)b * N_RES + n] = ss;
    }
  }
}

// ---------------------------------------------------------------------------
// kC_partial: split-K output GEMM. blockIdx = dtile(256) + 256*kc(4); each
// block reduces 512 n's for 4 d's x 32 b x {real,imag}. 1024 blocks.
// ---------------------------------------------------------------------------
__global__ __launch_bounds__(256) void kC_partial(const float* __restrict__ cos_sum,
                                                  const float* __restrict__ sin_sum,
                                                  const float* __restrict__ orw,
                                                  const float* __restrict__ oiw,
                                                  float* __restrict__ pr,
                                                  float* __restrict__ pi) {
  const int tid  = threadIdx.x;
  const int lane = tid & 63;
  const int wave = tid >> 6;
  const int d0 = (blockIdx.x & 255) * 4;
  const int kc = blockIdx.x >> 8;
  const int b0 = wave * 8;
  const int jbase = kc * 128;  // f4 idx base over n (512 f4 per row total)

  float ar[8][4], ai[8][4];
#pragma unroll
  for (int b = 0; b < 8; ++b)
#pragma unroll
    for (int d = 0; d < 4; ++d) { ar[b][d] = 0.f; ai[b][d] = 0.f; }

#pragma unroll 1
  for (int i = 0; i < 2; ++i) {
    const int j = jbase + lane + 64 * i;
    float4 wr[4], wi[4];
#pragma unroll
    for (int d = 0; d < 4; ++d) {
      wr[d] = ((const float4*)(orw + (size_t)(d0 + d) * N_RES))[j];
      wi[d] = ((const float4*)(oiw + (size_t)(d0 + d) * N_RES))[j];
    }
#pragma unroll
    for (int b = 0; b < 8; ++b) {
      float4 cs = ((const float4*)(cos_sum + (size_t)(b0 + b) * N_RES))[j];
      float4 sn = ((const float4*)(sin_sum + (size_t)(b0 + b) * N_RES))[j];
#pragma unroll
      for (int d = 0; d < 4; ++d) {
        ar[b][d] += cs.x * wr[d].x + cs.y * wr[d].y + cs.z * wr[d].z + cs.w * wr[d].w;
        ai[b][d] += sn.x * wi[d].x + sn.y * wi[d].y + sn.z * wi[d].z + sn.w * wi[d].w;
      }
    }
  }

#pragma unroll
  for (int b = 0; b < 8; ++b) {
#pragma unroll
    for (int d = 0; d < 4; ++d) {
      float vr = ar[b][d];
      float vi = ai[b][d];
#pragma unroll
      for (int m = 32; m >= 1; m >>= 1) {
        vr += __shfl_xor(vr, m, 64);
        vi += __shfl_xor(vi, m, 64);
      }
      if (lane == 0) {
        const size_t o = (size_t)(kc * BATCH + b0 + b) * D_MODEL + d0 + d;
        pr[o] = vr;
        pi[o] = vi;
      }
    }
  }
}

// kC2: out = silu(sum_kc partials). 8192 float4 per component -> 32 blocks.
__device__ __forceinline__ float silu(float v) { return v / (1.f + __expf(-v)); }

__global__ __launch_bounds__(256) void kC2(const float* __restrict__ pr,
                                           const float* __restrict__ pi,
                                           float* __restrict__ out) {
  const int idx = blockIdx.x * 256 + threadIdx.x;  // f4 idx over 32*256
  const float4* pr4 = (const float4*)pr;
  const float4* pi4 = (const float4*)pi;
  float4 vr = pr4[idx];
  float4 vi = pi4[idx];
#pragma unroll
  for (int kc = 1; kc < 4; ++kc) {
    float4 a = pr4[kc * 8192 + idx];
    float4 b = pi4[kc * 8192 + idx];
    vr.x += a.x; vr.y += a.y; vr.z += a.z; vr.w += a.w;
    vi.x += b.x; vi.y += b.y; vi.z += b.z; vi.w += b.w;
  }
  float4 orr, oii;
  orr.x = silu(vr.x); orr.y = silu(vr.y); orr.z = silu(vr.z); orr.w = silu(vr.w);
  oii.x = silu(vi.x); oii.y = silu(vi.y); oii.z = silu(vi.z); oii.w = silu(vi.w);
  ((float4*)out)[idx] = orr;
  ((float4*)out)[8192 + idx] = oii;
}

extern "C" void kernel_launch(void* const* d_in, const int* in_sizes, int n_in,
                              void* d_out, int out_size, void* d_ws, size_t ws_size,
                              hipStream_t stream) {
  const float* xr   = (const float*)d_in[0];
  const float* xi   = (const float*)d_in[1];
  const float* t    = (const float*)d_in[2];
  const float* ipw  = (const float*)d_in[3];
  const float* bias = (const float*)d_in[4];
  const float* W    = (const float*)d_in[5];
  const float* Bm   = (const float*)d_in[6];
  const float* orw  = (const float*)d_in[7];
  const float* oiw  = (const float*)d_in[8];
  float* out = (float*)d_out;

  float* ws      = (float*)d_ws;
  float* xc      = ws + WS_XC;
  float* cos_sum = ws + WS_CS;
  float* sin_sum = ws + WS_SS;
  float* pa      = ws + WS_PA;
  float* pr      = ws + WS_PR;
  float* pi      = ws + WS_PI;

  kA_partial<<<512, 256, 0, stream>>>(xr, xi, ipw, pa);
  kA2<<<32, 256, 0, stream>>>(pa, bias, xc);
  kB<<<N_RES, 256, 0, stream>>>(xc, W, Bm, t, cos_sum, sin_sum);
  kC_partial<<<1024, 256, 0, stream>>>(cos_sum, sin_sum, orw, oiw, pr, pi);
  kC2<<<32, 256, 0, stream>>>(pr, pi, out);
}